// Round 18
// baseline (1576.732 us; speedup 1.0000x reference)
//
#include <hip/hip_runtime.h>
#include <hip/hip_bf16.h>
#include <cstdint>

#define N_NODES 100000
#define NPAD    100032   // padded row count (multiple of 64)
#define N_EDGES 3200000
#define HID 256
#define NG 16
#define BN_EPS 1e-5f
#define B0 120       // bn0stats partial blocks
#define NB 391       // scan blocks (391*256 >= N_NODES)
#define SLABS 128    // stats atomic slabs
#define FPART 50000  // k_fill column-partition width (2 * 50000 = 100000)
#define LDSROW 264   // padded LDS row stride in elements
#define AGB 4096     // k_agg / k_l1fused grid blocks
#define NGRP (N_NODES / 4)   // 25000 node-groups of 4
#define FB 16        // fold256 blocks
#define PCH 48       // k_aggpool nodes per block (multiple of 4; 2084 blocks)
#define PBLK ((N_NODES + PCH - 1) / PCH)

typedef unsigned short u16;
using bf16x8 = __attribute__((ext_vector_type(8))) short;
using f32x4  = __attribute__((ext_vector_type(4))) float;

__device__ __forceinline__ float bf2f(u16 b) {
    return __uint_as_float(((unsigned)b) << 16);
}
__device__ __forceinline__ u16 f2bf(float f) {
    unsigned u = __float_as_uint(f);
    unsigned r = (u + 0x7FFFu + ((u >> 16) & 1u)) >> 16;
    return (u16)r;
}
__device__ __forceinline__ float4 ld_bf16x4(const u16* p) {
    ushort4 u = *reinterpret_cast<const ushort4*>(p);
    float4 f;
    f.x = bf2f(u.x); f.y = bf2f(u.y); f.z = bf2f(u.z); f.w = bf2f(u.w);
    return f;
}

// ---------------- CSR build ----------------
__global__ void k_count(const int* __restrict__ coli, int* __restrict__ cnt) {
    int i = blockIdx.x * blockDim.x + threadIdx.x;
    int st = gridDim.x * blockDim.x;
    for (; i < N_EDGES; i += st) atomicAdd(&cnt[coli[i]], 1);
}

// ---- parallel 3-pass scan: A) block sums  B) scan sums  C) apply + dinv ----
__global__ __launch_bounds__(256) void k_scanA(const int* __restrict__ cnt,
                                               int* __restrict__ bsum) {
    const int t = threadIdx.x;
    const int i = blockIdx.x * 256 + t;
    int v = (i < N_NODES) ? cnt[i] : 0;
    for (int o = 32; o > 0; o >>= 1) v += __shfl_down(v, o);
    __shared__ int ws[4];
    if ((t & 63) == 0) ws[t >> 6] = v;
    __syncthreads();
    if (t == 0) bsum[blockIdx.x] = ws[0] + ws[1] + ws[2] + ws[3];
}

__global__ __launch_bounds__(512) void k_scanB(const int* __restrict__ bsum,
                                               int* __restrict__ boff,
                                               int* __restrict__ ptrN) {
    const int t = threadIdx.x;
    const int ln = t & 63, wv = t >> 6;
    int v = (t < NB) ? bsum[t] : 0;
    int sc = v;
    for (int o = 1; o < 64; o <<= 1) { int u = __shfl_up(sc, o); if (ln >= o) sc += u; }
    __shared__ int ws[8], wx[9];
    if (ln == 63) ws[wv] = sc;
    __syncthreads();
    if (t == 0) { int a = 0; for (int k = 0; k < 8; ++k) { wx[k] = a; a += ws[k]; } wx[8] = a; }
    __syncthreads();
    int excl = wx[wv] + sc - v;
    if (t < NB) boff[t] = excl;
    if (t == 0) ptrN[0] = wx[8];
}

__global__ __launch_bounds__(256) void k_scanC(const int* __restrict__ cnt,
                                               const int* __restrict__ boff,
                                               int* __restrict__ ptr,
                                               int* __restrict__ ptr2,
                                               float* __restrict__ dinv) {
    const int t = threadIdx.x;
    const int i = blockIdx.x * 256 + t;
    const int ln = t & 63, wv = t >> 6;
    int v = (i < N_NODES) ? cnt[i] : 0;
    if (i < N_NODES) dinv[i] = rsqrtf((float)v + 1.0f);
    int sc = v;
    for (int o = 1; o < 64; o <<= 1) { int u = __shfl_up(sc, o); if (ln >= o) sc += u; }
    __shared__ int ws[4], wx[4];
    if (ln == 63) ws[wv] = sc;
    __syncthreads();
    if (t == 0) { int a = 0; for (int k = 0; k < 4; ++k) { wx[k] = a; a += ws[k]; } }
    __syncthreads();
    int excl = boff[blockIdx.x] + wx[wv] + sc - v;
    if (i < N_NODES) { ptr[i] = excl; ptr2[i] = excl; }
}

// partitioned fill: this pass only handles cols in [lo, lo+FPART).
__global__ void k_fillp(const int* __restrict__ rowi, const int* __restrict__ coli,
                        int* __restrict__ ptr2, int* __restrict__ esrc, int lo) {
    int i = blockIdx.x * blockDim.x + threadIdx.x;
    int st = gridDim.x * blockDim.x;
    const int hi = lo + FPART;
    for (; i < N_EDGES; i += st) {
        int c = coli[i];
        if (c >= lo && c < hi) {
            int r = rowi[i];
            int p = atomicAdd(&ptr2[c], 1);
            esrc[p] = r;
        }
    }
}

// ---------------- BN0 stats + batch histogram fused ----------------
__global__ __launch_bounds__(256) void k_bn0stats(const float* __restrict__ pos,
                                                  const float* __restrict__ nrm,
                                                  const int* __restrict__ batch,
                                                  float* __restrict__ part /* B0*12 */,
                                                  int* __restrict__ cg) {
    __shared__ int h[NG];
    if (threadIdx.x < NG) h[threadIdx.x] = 0;
    __syncthreads();
    float s[6] = {0, 0, 0, 0, 0, 0}, q[6] = {0, 0, 0, 0, 0, 0};
    int i = blockIdx.x * blockDim.x + threadIdx.x;
    int stp = gridDim.x * blockDim.x;
    for (; i < N_NODES; i += stp) {
        float v;
        v = pos[i * 3 + 0]; s[0] += v; q[0] += v * v;
        v = pos[i * 3 + 1]; s[1] += v; q[1] += v * v;
        v = pos[i * 3 + 2]; s[2] += v; q[2] += v * v;
        v = nrm[i * 3 + 0]; s[3] += v; q[3] += v * v;
        v = nrm[i * 3 + 1]; s[4] += v; q[4] += v * v;
        v = nrm[i * 3 + 2]; s[5] += v; q[5] += v * v;
        atomicAdd(&h[batch[i]], 1);
    }
#pragma unroll
    for (int k = 0; k < 6; ++k) {
        for (int o = 32; o > 0; o >>= 1) { s[k] += __shfl_down(s[k], o); q[k] += __shfl_down(q[k], o); }
    }
    __shared__ float ls[4][12];
    const int wv = threadIdx.x >> 6;
    const int ln = threadIdx.x & 63;
    if (ln == 0) {
#pragma unroll
        for (int k = 0; k < 6; ++k) { ls[wv][k] = s[k]; ls[wv][6 + k] = q[k]; }
    }
    __syncthreads();
    if (threadIdx.x < 12)
        part[blockIdx.x * 12 + threadIdx.x] =
            ls[0][threadIdx.x] + ls[1][threadIdx.x] + ls[2][threadIdx.x] + ls[3][threadIdx.x];
    if (threadIdx.x < NG) {
        int v = h[threadIdx.x];
        if (v) atomicAdd(&cg[threadIdx.x], v);
    }
}

// ---------------- fold BN0 into W1 (K=6): Wf=A*W, rvB = B^T W ----------------
__global__ void k_fold6(const float* __restrict__ W,
                        const float* __restrict__ part, float invcnt,
                        const float* __restrict__ gamma, const float* __restrict__ beta,
                        float* __restrict__ Wf, float* __restrict__ rvB) {
    __shared__ float st[12];
    int c = threadIdx.x;
    if (c < 12) {
        float a = 0.f;
        for (int b = 0; b < B0; ++b) a += part[b * 12 + c];
        st[c] = a;
    }
    __syncthreads();
    float acc = 0.f;
    for (int k = 0; k < 6; ++k) {
        float m = st[k] * invcnt;
        float var = st[6 + k] * invcnt - m * m;
        float A = gamma[k] * rsqrtf(var + BN_EPS);
        float B = beta[k] - m * A;
        float w = W[k * HID + c];
        Wf[k * HID + c] = A * w;
        acc = fmaf(B, w, acc);
    }
    rvB[c] = acc;
}

// -------- fold for K=256: FB blocks; block b transforms k-slice, block 0 does rv --
__global__ void k_fold256(const float* __restrict__ W,
                          const float* __restrict__ partL /* SLABS*512 */, float invcnt,
                          const float* __restrict__ gamma, const float* __restrict__ beta,
                          u16* __restrict__ WhiT, u16* __restrict__ WloT,
                          float* __restrict__ rv) {
    __shared__ float ss[HID], sq[HID];
    int c = threadIdx.x;
    {
        float a = 0.f, b = 0.f;
#pragma unroll 4
        for (int bb = 0; bb < SLABS; ++bb) {
            a += partL[bb * 512 + c];
            b += partL[bb * 512 + HID + c];
        }
        ss[c] = a; sq[c] = b;
    }
    __syncthreads();
    const int k0 = blockIdx.x * (HID / FB);
#pragma unroll
    for (int kk = 0; kk < HID / FB; ++kk) {
        int k = k0 + kk;
        float m = ss[k] * invcnt;
        float var = sq[k] * invcnt - m * m;
        float A = gamma[k] * rsqrtf(var + BN_EPS);
        float w = W[k * HID + c];
        float wf = A * w;
        u16 hi = f2bf(wf);
        WhiT[c * HID + k] = hi;
        WloT[c * HID + k] = f2bf(wf - bf2f(hi));
    }
    if (blockIdx.x == 0) {
        float acc = 0.f;
        for (int k = 0; k < HID; ++k) {
            float m = ss[k] * invcnt;
            float var = sq[k] * invcnt - m * m;
            float A = gamma[k] * rsqrtf(var + BN_EPS);
            float B = beta[k] - m * A;
            acc = fmaf(B, W[k * HID + c], acc);
        }
        rv[c] = acc;
    }
}

// ------- layer 1 FUSED: aggregation + tiny GEMM + relu + stats; grid-stride ------
__global__ __launch_bounds__(256) void k_l1fused(
    const float* __restrict__ pos, const float* __restrict__ nrm,
    const int* __restrict__ ptr, const int* __restrict__ esrc,
    const float* __restrict__ dinv, const float* __restrict__ Wf,
    const float* __restrict__ rvB, const float* __restrict__ b1,
    u16* __restrict__ out, float* __restrict__ partL) {
    const int wv = threadIdx.x >> 6;
    const int ln = threadIdx.x & 63;
    float w[6][4], rv4[4], bb4[4];
#pragma unroll
    for (int k = 0; k < 6; ++k) {
        float4 t = *reinterpret_cast<const float4*>(&Wf[k * HID + ln * 4]);
        w[k][0] = t.x; w[k][1] = t.y; w[k][2] = t.z; w[k][3] = t.w;
    }
    {
        float4 t = *reinterpret_cast<const float4*>(&rvB[ln * 4]);
        rv4[0] = t.x; rv4[1] = t.y; rv4[2] = t.z; rv4[3] = t.w;
        float4 u = *reinterpret_cast<const float4*>(&b1[ln * 4]);
        bb4[0] = u.x; bb4[1] = u.y; bb4[2] = u.z; bb4[3] = u.w;
    }
    float ssr[4] = {0, 0, 0, 0}, qqr[4] = {0, 0, 0, 0};
    for (int n = blockIdx.x * 4 + wv; n < N_NODES; n += AGB * 4) {
        const float dn = dinv[n];
        float z0 = 0, z1 = 0, z2 = 0, z3 = 0, z4 = 0, z5 = 0, t = 0;
        const int s_ = ptr[n], e_ = ptr[n + 1];
        for (int e = s_ + ln; e < e_; e += 64) {
            int src = esrc[e];
            float we = dn * dinv[src];
            z0 = fmaf(we, pos[src * 3 + 0], z0);
            z1 = fmaf(we, pos[src * 3 + 1], z1);
            z2 = fmaf(we, pos[src * 3 + 2], z2);
            z3 = fmaf(we, nrm[src * 3 + 0], z3);
            z4 = fmaf(we, nrm[src * 3 + 1], z4);
            z5 = fmaf(we, nrm[src * 3 + 2], z5);
            t += we;
        }
        if (ln == 0) {
            float sl = dn * dn;
            z0 = fmaf(sl, pos[n * 3 + 0], z0);
            z1 = fmaf(sl, pos[n * 3 + 1], z1);
            z2 = fmaf(sl, pos[n * 3 + 2], z2);
            z3 = fmaf(sl, nrm[n * 3 + 0], z3);
            z4 = fmaf(sl, nrm[n * 3 + 1], z4);
            z5 = fmaf(sl, nrm[n * 3 + 2], z5);
            t += sl;
        }
#pragma unroll
        for (int o = 1; o < 64; o <<= 1) {
            z0 += __shfl_xor(z0, o); z1 += __shfl_xor(z1, o); z2 += __shfl_xor(z2, o);
            z3 += __shfl_xor(z3, o); z4 += __shfl_xor(z4, o); z5 += __shfl_xor(z5, o);
            t  += __shfl_xor(t, o);
        }
        ushort4 o4;
#pragma unroll
        for (int j = 0; j < 4; ++j) {
            float oj = fmaf(t, rv4[j], bb4[j]);
            oj = fmaf(z0, w[0][j], oj); oj = fmaf(z1, w[1][j], oj); oj = fmaf(z2, w[2][j], oj);
            oj = fmaf(z3, w[3][j], oj); oj = fmaf(z4, w[4][j], oj); oj = fmaf(z5, w[5][j], oj);
            oj = fmaxf(oj, 0.f);
            ssr[j] += oj; qqr[j] = fmaf(oj, oj, qqr[j]);
            ((u16*)&o4)[j] = f2bf(oj);
        }
        *reinterpret_cast<ushort4*>(&out[(size_t)n * HID + ln * 4]) = o4;
    }
    __shared__ float sh[4 * 512];
    float* shw = &sh[wv * 512];
#pragma unroll
    for (int j = 0; j < 4; ++j) { shw[ln * 4 + j] = ssr[j]; shw[256 + ln * 4 + j] = qqr[j]; }
    __syncthreads();
    const int t = threadIdx.x;
    float S = sh[t] + sh[512 + t] + sh[1024 + t] + sh[1536 + t];
    float Q = sh[256 + t] + sh[768 + t] + sh[1280 + t] + sh[1792 + t];
    float* slab = &partL[(size_t)(blockIdx.x & (SLABS - 1)) * 512];
    atomicAdd(&slab[t], S);
    atomicAdd(&slab[256 + t], Q);
}

// ------ MFMA GEMM, LDS-staged A tile (padded rows, 2-way-free bank spread) ------
__global__ __launch_bounds__(256) void k_gemm_lds(
    const u16* __restrict__ X, const u16* __restrict__ WhiT,
    const u16* __restrict__ WloT, const float* __restrict__ rv,
    u16* __restrict__ out) {
    __shared__ u16 As[64 * LDSROW];
    const int tid = threadIdx.x;
    const int wv = tid >> 6;
    const int ln = tid & 63;
    const int row0 = blockIdx.x * 64;
    const int lr = ln & 15;
    const int lk = (ln >> 4) * 8;
    const int wcol0 = wv * 64;

#pragma unroll
    for (int i = 0; i < 8; ++i) {
        int chunk = i * 256 + tid;
        int r = chunk >> 5;
        int kc = chunk & 31;
        bf16x8 v = *reinterpret_cast<const bf16x8*>(&X[(size_t)(row0 + r) * HID + kc * 8]);
        *reinterpret_cast<bf16x8*>(&As[r * LDSROW + kc * 8]) = v;
    }
    __syncthreads();

    f32x4 acc[4][4] = {};
    for (int kk = 0; kk < HID; kk += 32) {
        bf16x8 a[4], bh[4], bl[4];
#pragma unroll
        for (int i = 0; i < 4; ++i)
            a[i] = *reinterpret_cast<const bf16x8*>(&As[(i * 16 + lr) * LDSROW + kk + lk]);
#pragma unroll
        for (int c = 0; c < 4; ++c) {
            int col = wcol0 + c * 16 + lr;
            bh[c] = *reinterpret_cast<const bf16x8*>(&WhiT[(size_t)col * HID + kk + lk]);
            bl[c] = *reinterpret_cast<const bf16x8*>(&WloT[(size_t)col * HID + kk + lk]);
        }
#pragma unroll
        for (int i = 0; i < 4; ++i)
#pragma unroll
            for (int c = 0; c < 4; ++c) {
                acc[i][c] = __builtin_amdgcn_mfma_f32_16x16x32_bf16(a[i], bh[c], acc[i][c], 0, 0, 0);
                acc[i][c] = __builtin_amdgcn_mfma_f32_16x16x32_bf16(a[i], bl[c], acc[i][c], 0, 0, 0);
            }
    }
    const int crow = (ln >> 4) * 4;
#pragma unroll
    for (int c = 0; c < 4; ++c) {
        int col = wcol0 + c * 16 + lr;
        float rvc = rv[col];
#pragma unroll
        for (int i = 0; i < 4; ++i) {
#pragma unroll
            for (int rg = 0; rg < 4; ++rg) {
                int r = row0 + i * 16 + crow + rg;
                out[(size_t)r * HID + col] = f2bf(acc[i][c][rg] + rvc);
            }
        }
    }
}

// ---- gather body shared by k_agg / k_aggpool: returns relu(S.xw + bias) ----
__device__ __forceinline__ void agg_node(const u16* __restrict__ xw,
                                         const int* __restrict__ ptr,
                                         const int* __restrict__ esrc,
                                         const float* __restrict__ dinv,
                                         int n, int ln, const float4& b,
                                         float& a0, float& a1, float& a2, float& a3) {
    const float dn = dinv[n];
    float4 v = ld_bf16x4(&xw[(size_t)n * HID + ln * 4]);
    const float sl = dn * dn;
    a0 = v.x * sl; a1 = v.y * sl; a2 = v.z * sl; a3 = v.w * sl;
    const int s = ptr[n], e = ptr[n + 1];
    for (int bs = s; bs < e; bs += 64) {
        const int cnt = (e - bs < 64) ? e - bs : 64;
        int myidx = 0;
        float myw = 0.f;
        if (ln < cnt) {
            myidx = esrc[bs + ln];
            myw = dinv[myidx] * dn;
        }
        int j = 0;
        for (; j + 7 < cnt; j += 8) {
            int   s0 = __shfl(myidx, j),     s1 = __shfl(myidx, j + 1);
            int   s2 = __shfl(myidx, j + 2), s3 = __shfl(myidx, j + 3);
            int   s4 = __shfl(myidx, j + 4), s5 = __shfl(myidx, j + 5);
            int   s6 = __shfl(myidx, j + 6), s7 = __shfl(myidx, j + 7);
            float w0 = __shfl(myw, j),       w1 = __shfl(myw, j + 1);
            float w2 = __shfl(myw, j + 2),   w3 = __shfl(myw, j + 3);
            float w4 = __shfl(myw, j + 4),   w5 = __shfl(myw, j + 5);
            float w6 = __shfl(myw, j + 6),   w7 = __shfl(myw, j + 7);
            float4 u0 = ld_bf16x4(&xw[(size_t)s0 * HID + ln * 4]);
            float4 u1 = ld_bf16x4(&xw[(size_t)s1 * HID + ln * 4]);
            float4 u2 = ld_bf16x4(&xw[(size_t)s2 * HID + ln * 4]);
            float4 u3 = ld_bf16x4(&xw[(size_t)s3 * HID + ln * 4]);
            float4 u4 = ld_bf16x4(&xw[(size_t)s4 * HID + ln * 4]);
            float4 u5 = ld_bf16x4(&xw[(size_t)s5 * HID + ln * 4]);
            float4 u6 = ld_bf16x4(&xw[(size_t)s6 * HID + ln * 4]);
            float4 u7 = ld_bf16x4(&xw[(size_t)s7 * HID + ln * 4]);
            a0 = fmaf(w0, u0.x, a0); a1 = fmaf(w0, u0.y, a1);
            a2 = fmaf(w0, u0.z, a2); a3 = fmaf(w0, u0.w, a3);
            a0 = fmaf(w1, u1.x, a0); a1 = fmaf(w1, u1.y, a1);
            a2 = fmaf(w1, u1.z, a2); a3 = fmaf(w1, u1.w, a3);
            a0 = fmaf(w2, u2.x, a0); a1 = fmaf(w2, u2.y, a1);
            a2 = fmaf(w2, u2.z, a2); a3 = fmaf(w2, u2.w, a3);
            a0 = fmaf(w3, u3.x, a0); a1 = fmaf(w3, u3.y, a1);
            a2 = fmaf(w3, u3.z, a2); a3 = fmaf(w3, u3.w, a3);
            a0 = fmaf(w4, u4.x, a0); a1 = fmaf(w4, u4.y, a1);
            a2 = fmaf(w4, u4.z, a2); a3 = fmaf(w4, u4.w, a3);
            a0 = fmaf(w5, u5.x, a0); a1 = fmaf(w5, u5.y, a1);
            a2 = fmaf(w5, u5.z, a2); a3 = fmaf(w5, u5.w, a3);
            a0 = fmaf(w6, u6.x, a0); a1 = fmaf(w6, u6.y, a1);
            a2 = fmaf(w6, u6.z, a2); a3 = fmaf(w6, u6.w, a3);
            a0 = fmaf(w7, u7.x, a0); a1 = fmaf(w7, u7.y, a1);
            a2 = fmaf(w7, u7.z, a2); a3 = fmaf(w7, u7.w, a3);
        }
        for (; j < cnt; ++j) {
            int   s0 = __shfl(myidx, j);
            float w0 = __shfl(myw, j);
            float4 u0 = ld_bf16x4(&xw[(size_t)s0 * HID + ln * 4]);
            a0 = fmaf(w0, u0.x, a0); a1 = fmaf(w0, u0.y, a1);
            a2 = fmaf(w0, u0.z, a2); a3 = fmaf(w0, u0.w, a3);
        }
    }
    a0 = fmaxf(a0 + b.x, 0.f);
    a1 = fmaxf(a1 + b.y, 0.f);
    a2 = fmaxf(a2 + b.z, 0.f);
    a3 = fmaxf(a3 + b.w, 0.f);
}

// ---- aggregation + stats; grid-stride (AGB blocks, 2 HW scheduling waves) ----
__global__ __launch_bounds__(256) void k_agg(
    const u16* __restrict__ xw, const int* __restrict__ ptr,
    const int* __restrict__ esrc, const float* __restrict__ dinv,
    const float* __restrict__ bias, u16* __restrict__ y,
    float* __restrict__ partL) {
    const int wv = threadIdx.x >> 6;
    const int ln = threadIdx.x & 63;
    float4 b = *reinterpret_cast<const float4*>(&bias[ln * 4]);
    float ssr[4] = {0, 0, 0, 0}, qqr[4] = {0, 0, 0, 0};
    for (int g = blockIdx.x; g < NGRP; g += AGB) {
        const int n = g * 4 + wv;
        float a0, a1, a2, a3;
        agg_node(xw, ptr, esrc, dinv, n, ln, b, a0, a1, a2, a3);
        ssr[0] += a0; qqr[0] = fmaf(a0, a0, qqr[0]);
        ssr[1] += a1; qqr[1] = fmaf(a1, a1, qqr[1]);
        ssr[2] += a2; qqr[2] = fmaf(a2, a2, qqr[2]);
        ssr[3] += a3; qqr[3] = fmaf(a3, a3, qqr[3]);
        ushort4 o;
        o.x = f2bf(a0); o.y = f2bf(a1); o.z = f2bf(a2); o.w = f2bf(a3);
        *reinterpret_cast<ushort4*>(&y[(size_t)n * HID + ln * 4]) = o;
    }
    __shared__ float sh[4 * 512];
    float* shw = &sh[wv * 512];
#pragma unroll
    for (int j = 0; j < 4; ++j) { shw[ln * 4 + j] = ssr[j]; shw[256 + ln * 4 + j] = qqr[j]; }
    __syncthreads();
    const int t = threadIdx.x;
    float S = sh[t] + sh[512 + t] + sh[1024 + t] + sh[1536 + t];
    float Q = sh[256 + t] + sh[768 + t] + sh[1280 + t] + sh[1792 + t];
    float* slab = &partL[(size_t)(blockIdx.x & (SLABS - 1)) * 512];
    atomicAdd(&slab[t], S);
    atomicAdd(&slab[256 + t], Q);
}

// ---- LAST layer: aggregation + stats + fused pool (contiguous chunks, no y) ----
__global__ __launch_bounds__(256) void k_aggpool(
    const u16* __restrict__ xw, const int* __restrict__ ptr,
    const int* __restrict__ esrc, const float* __restrict__ dinv,
    const float* __restrict__ bias, const int* __restrict__ batch,
    float* __restrict__ partL, float* __restrict__ ps) {
    const int wv = threadIdx.x >> 6;
    const int ln = threadIdx.x & 63;
    float4 b = *reinterpret_cast<const float4*>(&bias[ln * 4]);
    float ssr[4] = {0, 0, 0, 0}, qqr[4] = {0, 0, 0, 0};
    const int n0 = blockIdx.x * PCH;
    const int n1 = (n0 + PCH < N_NODES) ? n0 + PCH : N_NODES;
    int curg = -1;
    float p0 = 0, p1 = 0, p2 = 0, p3 = 0;
    for (int n = n0 + wv; n < n1; n += 4) {
        float a0, a1, a2, a3;
        agg_node(xw, ptr, esrc, dinv, n, ln, b, a0, a1, a2, a3);
        ssr[0] += a0; qqr[0] = fmaf(a0, a0, qqr[0]);
        ssr[1] += a1; qqr[1] = fmaf(a1, a1, qqr[1]);
        ssr[2] += a2; qqr[2] = fmaf(a2, a2, qqr[2]);
        ssr[3] += a3; qqr[3] = fmaf(a3, a3, qqr[3]);
        int g = batch[n];   // wave-uniform
        if (g != curg) {
            if (curg >= 0) {
                atomicAdd(&ps[curg * HID + ln * 4 + 0], p0);
                atomicAdd(&ps[curg * HID + ln * 4 + 1], p1);
                atomicAdd(&ps[curg * HID + ln * 4 + 2], p2);
                atomicAdd(&ps[curg * HID + ln * 4 + 3], p3);
            }
            curg = g;
            p0 = p1 = p2 = p3 = 0.f;
        }
        p0 += a0; p1 += a1; p2 += a2; p3 += a3;
    }
    if (curg >= 0) {
        atomicAdd(&ps[curg * HID + ln * 4 + 0], p0);
        atomicAdd(&ps[curg * HID + ln * 4 + 1], p1);
        atomicAdd(&ps[curg * HID + ln * 4 + 2], p2);
        atomicAdd(&ps[curg * HID + ln * 4 + 3], p3);
    }
    __shared__ float sh[4 * 512];
    float* shw = &sh[wv * 512];
#pragma unroll
    for (int j = 0; j < 4; ++j) { shw[ln * 4 + j] = ssr[j]; shw[256 + ln * 4 + j] = qqr[j]; }
    __syncthreads();
    const int t = threadIdx.x;
    float S = sh[t] + sh[512 + t] + sh[1024 + t] + sh[1536 + t];
    float Q = sh[256 + t] + sh[768 + t] + sh[1280 + t] + sh[1792 + t];
    float* slab = &partL[(size_t)(blockIdx.x & (SLABS - 1)) * 512];
    atomicAdd(&slab[t], S);
    atomicAdd(&slab[256 + t], Q);
}

// ---------------- finalize: BN4 affine on pooled sums (reads slabs) ----------------
__global__ void k_final(const float* __restrict__ ps, const int* __restrict__ cg,
                        const float* __restrict__ partL, const float* __restrict__ gamma,
                        const float* __restrict__ beta, float* __restrict__ out) {
    __shared__ float ss[HID], sq[HID];
    const int c = threadIdx.x;
    {
        float a = 0.f, b = 0.f;
#pragma unroll 4
        for (int bb = 0; bb < SLABS; ++bb) {
            a += partL[bb * 512 + c];
            b += partL[bb * 512 + HID + c];
        }
        ss[c] = a; sq[c] = b;
    }
    __syncthreads();
    const float invn = 1.0f / (float)N_NODES;
    float m = ss[c] * invn;
    float var = sq[c] * invn - m * m;
    float A = gamma[c] * rsqrtf(var + BN_EPS);
    float B = beta[c] - m * A;
    for (int g = 0; g < NG; ++g) {
        float cn = (float)cg[g];
        float val = (A * ps[g * HID + c] + cn * B) / fmaxf(cn, 1.0f);
        out[g * HID + c] = val;
    }
}

extern "C" void kernel_launch(void* const* d_in, const int* in_sizes, int n_in,
                              void* d_out, int out_size, void* d_ws, size_t ws_size,
                              hipStream_t stream) {
    const float* pos   = (const float*)d_in[0];
    const float* nrm   = (const float*)d_in[1];
    const int*   ei    = (const int*)d_in[2];
    const int*   batch = (const int*)d_in[3];
    const float* bn0g  = (const float*)d_in[4];
    const float* bn0b  = (const float*)d_in[5];
    const float* W[4]   = {(const float*)d_in[6],  (const float*)d_in[10], (const float*)d_in[14], (const float*)d_in[18]};
    const float* bb[4]  = {(const float*)d_in[7],  (const float*)d_in[11], (const float*)d_in[15], (const float*)d_in[19]};
    const float* bg[4]  = {(const float*)d_in[8],  (const float*)d_in[12], (const float*)d_in[16], (const float*)d_in[20]};
    const float* bbt[4] = {(const float*)d_in[9],  (const float*)d_in[13], (const float*)d_in[17], (const float*)d_in[21]};

    char* wp = (char*)d_ws;
    auto alloc = [&](size_t bytes) {
        char* p = wp;
        wp += (bytes + 255) & ~(size_t)255;
        return p;
    };
    float* dinv  = (float*)alloc((size_t)N_NODES * 4);
    int*   cnt   = (int*)  alloc((size_t)N_NODES * 4);
    int*   ptr   = (int*)  alloc((size_t)(N_NODES + 1) * 4);
    int*   ptr2  = (int*)  alloc((size_t)N_NODES * 4);
    int*   esrc  = (int*)  alloc((size_t)N_EDGES * 4);
    int*   bsum  = (int*)  alloc((size_t)NB * 4);
    int*   boff  = (int*)  alloc((size_t)NB * 4);
    u16*   bufA  = (u16*)  alloc((size_t)NPAD * HID * 2);
    u16*   bufB  = (u16*)  alloc((size_t)NPAD * HID * 2);
    float* part0 = (float*)alloc((size_t)B0 * 12 * 4);
    float* partQ = (float*)alloc((size_t)4 * SLABS * 512 * 4);   // 4 ping-pong stat buffers
    float* Wf1   = (float*)alloc((size_t)6 * HID * 4);
    u16*   WhiT  = (u16*)  alloc((size_t)HID * HID * 2);
    u16*   WloT  = (u16*)  alloc((size_t)HID * HID * 2);
    float* rv    = (float*)alloc(HID * 4);
    float* psz   = (float*)alloc((size_t)(NG * HID + NG) * 4);
    float* ps    = psz;
    int*   cg    = (int*)(psz + NG * HID);
    (void)ws_size; (void)in_sizes; (void)n_in; (void)out_size;

    const int* rowi = ei;
    const int* coli = ei + N_EDGES;

    hipMemsetAsync(cnt, 0, (size_t)N_NODES * 4, stream);
    hipMemsetAsync(psz, 0, (size_t)(NG * HID + NG) * 4, stream);
    hipMemsetAsync(partQ, 0, (size_t)4 * SLABS * 512 * 4, stream);

    // CSR + norms (parallel 3-pass scan)
    k_count<<<2048, 256, 0, stream>>>(coli, cnt);
    k_scanA<<<NB, 256, 0, stream>>>(cnt, bsum);
    k_scanB<<<1, 512, 0, stream>>>(bsum, boff, &ptr[N_NODES]);
    k_scanC<<<NB, 256, 0, stream>>>(cnt, boff, ptr, ptr2, dinv);
    for (int p = 0; p < 2; ++p)
        k_fillp<<<1024, 256, 0, stream>>>(rowi, coli, ptr2, esrc, p * FPART);

    // layer 1: fused raw-space aggregation + BN0-folded tiny GEMM + stats
    k_bn0stats<<<B0, 256, 0, stream>>>(pos, nrm, batch, part0, cg);
    k_fold6<<<1, 256, 0, stream>>>(W[0], part0, 1.0f / (float)N_NODES, bn0g, bn0b, Wf1, rv);
    k_l1fused<<<AGB, 256, 0, stream>>>(pos, nrm, ptr, esrc, dinv, Wf1, rv, bb[0], bufA,
                                       &partQ[0]);

    // layers 2..3: fold -> MFMA gemm -> aggregate(+stats), ping-pong stat buffers
    for (int l = 0; l < 2; ++l) {
        k_fold256<<<FB, 256, 0, stream>>>(W[l + 1], &partQ[(size_t)l * SLABS * 512],
                                          1.0f / (float)N_NODES, bg[l], bbt[l],
                                          WhiT, WloT, rv);
        k_gemm_lds<<<NPAD / 64, 256, 0, stream>>>(bufA, WhiT, WloT, rv, bufB);
        k_agg<<<AGB, 256, 0, stream>>>(bufB, ptr, esrc, dinv, bb[l + 1], bufA,
                                       &partQ[(size_t)(l + 1) * SLABS * 512]);
    }

    // layer 4: fold -> gemm -> aggregate + fused pool (no y write)
    k_fold256<<<FB, 256, 0, stream>>>(W[3], &partQ[(size_t)2 * SLABS * 512],
                                      1.0f / (float)N_NODES, bg[2], bbt[2],
                                      WhiT, WloT, rv);
    k_gemm_lds<<<NPAD / 64, 256, 0, stream>>>(bufA, WhiT, WloT, rv, bufB);
    k_aggpool<<<PBLK, 256, 0, stream>>>(bufB, ptr, esrc, dinv, bb[3], batch,
                                        &partQ[(size_t)3 * SLABS * 512], ps);

    // final: BN4 applied analytically on pooled sums
    k_final<<<1, 256, 0, stream>>>(ps, cg, &partQ[(size_t)3 * SLABS * 512],
                                   bg[3], bbt[3], (float*)d_out);
}

// Round 19
// 1448.942 us; speedup vs baseline: 1.0882x; 1.0882x over previous
//
#include <hip/hip_runtime.h>
#include <hip/hip_bf16.h>
#include <cstdint>

#define N_NODES 100000
#define NPAD    100032   // padded row count (multiple of 64)
#define N_EDGES 3200000
#define HID 256
#define NG 16
#define BN_EPS 1e-5f
#define B0 120       // bn0stats partial blocks
#define NB 391       // scan blocks (391*256 >= N_NODES)
#define SLABS 128    // stats atomic slabs
#define FPART 25000  // k_fill column-partition width (4 * 25000 = 100000)
#define LDSROW 264   // padded LDS row stride in elements
#define AGB 4096     // k_agg / k_l1fused grid blocks
#define NGRP (N_NODES / 4)   // 25000 node-groups of 4
#define FB 16        // fold256 blocks
#define PCH 96       // k_aggpool nodes per block (multiple of 4)
#define PBLK ((N_NODES + PCH - 1) / PCH)

typedef unsigned short u16;
using bf16x8 = __attribute__((ext_vector_type(8))) short;
using f32x4  = __attribute__((ext_vector_type(4))) float;

__device__ __forceinline__ float bf2f(u16 b) {
    return __uint_as_float(((unsigned)b) << 16);
}
__device__ __forceinline__ u16 f2bf(float f) {
    unsigned u = __float_as_uint(f);
    unsigned r = (u + 0x7FFFu + ((u >> 16) & 1u)) >> 16;
    return (u16)r;
}
__device__ __forceinline__ float4 ld_bf16x4(const u16* p) {
    ushort4 u = *reinterpret_cast<const ushort4*>(p);
    float4 f;
    f.x = bf2f(u.x); f.y = bf2f(u.y); f.z = bf2f(u.z); f.w = bf2f(u.w);
    return f;
}

// ---------------- CSR build ----------------
__global__ void k_count(const int* __restrict__ coli, int* __restrict__ cnt) {
    int i = blockIdx.x * blockDim.x + threadIdx.x;
    int st = gridDim.x * blockDim.x;
    for (; i < N_EDGES; i += st) atomicAdd(&cnt[coli[i]], 1);
}

// ---- parallel 3-pass scan: A) block sums  B) scan sums  C) apply + dinv ----
__global__ __launch_bounds__(256) void k_scanA(const int* __restrict__ cnt,
                                               int* __restrict__ bsum) {
    const int t = threadIdx.x;
    const int i = blockIdx.x * 256 + t;
    int v = (i < N_NODES) ? cnt[i] : 0;
    for (int o = 32; o > 0; o >>= 1) v += __shfl_down(v, o);
    __shared__ int ws[4];
    if ((t & 63) == 0) ws[t >> 6] = v;
    __syncthreads();
    if (t == 0) bsum[blockIdx.x] = ws[0] + ws[1] + ws[2] + ws[3];
}

__global__ __launch_bounds__(512) void k_scanB(const int* __restrict__ bsum,
                                               int* __restrict__ boff,
                                               int* __restrict__ ptrN) {
    const int t = threadIdx.x;
    const int ln = t & 63, wv = t >> 6;
    int v = (t < NB) ? bsum[t] : 0;
    int sc = v;
    for (int o = 1; o < 64; o <<= 1) { int u = __shfl_up(sc, o); if (ln >= o) sc += u; }
    __shared__ int ws[8], wx[9];
    if (ln == 63) ws[wv] = sc;
    __syncthreads();
    if (t == 0) { int a = 0; for (int k = 0; k < 8; ++k) { wx[k] = a; a += ws[k]; } wx[8] = a; }
    __syncthreads();
    int excl = wx[wv] + sc - v;
    if (t < NB) boff[t] = excl;
    if (t == 0) ptrN[0] = wx[8];
}

__global__ __launch_bounds__(256) void k_scanC(const int* __restrict__ cnt,
                                               const int* __restrict__ boff,
                                               int* __restrict__ ptr,
                                               int* __restrict__ ptr2,
                                               float* __restrict__ dinv) {
    const int t = threadIdx.x;
    const int i = blockIdx.x * 256 + t;
    const int ln = t & 63, wv = t >> 6;
    int v = (i < N_NODES) ? cnt[i] : 0;
    if (i < N_NODES) dinv[i] = rsqrtf((float)v + 1.0f);
    int sc = v;
    for (int o = 1; o < 64; o <<= 1) { int u = __shfl_up(sc, o); if (ln >= o) sc += u; }
    __shared__ int ws[4], wx[4];
    if (ln == 63) ws[wv] = sc;
    __syncthreads();
    if (t == 0) { int a = 0; for (int k = 0; k < 4; ++k) { wx[k] = a; a += ws[k]; } }
    __syncthreads();
    int excl = boff[blockIdx.x] + wx[wv] + sc - v;
    if (i < N_NODES) { ptr[i] = excl; ptr2[i] = excl; }
}

// partitioned fill: this pass only handles cols in [lo, lo+FPART).
__global__ void k_fillp(const int* __restrict__ rowi, const int* __restrict__ coli,
                        int* __restrict__ ptr2, int* __restrict__ esrc, int lo) {
    int i = blockIdx.x * blockDim.x + threadIdx.x;
    int st = gridDim.x * blockDim.x;
    const int hi = lo + FPART;
    for (; i < N_EDGES; i += st) {
        int c = coli[i];
        if (c >= lo && c < hi) {
            int r = rowi[i];
            int p = atomicAdd(&ptr2[c], 1);
            esrc[p] = r;
        }
    }
}

// ---------------- BN0 stats + batch histogram fused ----------------
__global__ __launch_bounds__(256) void k_bn0stats(const float* __restrict__ pos,
                                                  const float* __restrict__ nrm,
                                                  const int* __restrict__ batch,
                                                  float* __restrict__ part /* B0*12 */,
                                                  int* __restrict__ cg) {
    __shared__ int h[NG];
    if (threadIdx.x < NG) h[threadIdx.x] = 0;
    __syncthreads();
    float s[6] = {0, 0, 0, 0, 0, 0}, q[6] = {0, 0, 0, 0, 0, 0};
    int i = blockIdx.x * blockDim.x + threadIdx.x;
    int stp = gridDim.x * blockDim.x;
    for (; i < N_NODES; i += stp) {
        float v;
        v = pos[i * 3 + 0]; s[0] += v; q[0] += v * v;
        v = pos[i * 3 + 1]; s[1] += v; q[1] += v * v;
        v = pos[i * 3 + 2]; s[2] += v; q[2] += v * v;
        v = nrm[i * 3 + 0]; s[3] += v; q[3] += v * v;
        v = nrm[i * 3 + 1]; s[4] += v; q[4] += v * v;
        v = nrm[i * 3 + 2]; s[5] += v; q[5] += v * v;
        atomicAdd(&h[batch[i]], 1);
    }
#pragma unroll
    for (int k = 0; k < 6; ++k) {
        for (int o = 32; o > 0; o >>= 1) { s[k] += __shfl_down(s[k], o); q[k] += __shfl_down(q[k], o); }
    }
    __shared__ float ls[4][12];
    const int wv = threadIdx.x >> 6;
    const int ln = threadIdx.x & 63;
    if (ln == 0) {
#pragma unroll
        for (int k = 0; k < 6; ++k) { ls[wv][k] = s[k]; ls[wv][6 + k] = q[k]; }
    }
    __syncthreads();
    if (threadIdx.x < 12)
        part[blockIdx.x * 12 + threadIdx.x] =
            ls[0][threadIdx.x] + ls[1][threadIdx.x] + ls[2][threadIdx.x] + ls[3][threadIdx.x];
    if (threadIdx.x < NG) {
        int v = h[threadIdx.x];
        if (v) atomicAdd(&cg[threadIdx.x], v);
    }
}

// ---------------- fold BN0 into W1 (K=6): Wf=A*W, rvB = B^T W ----------------
__global__ void k_fold6(const float* __restrict__ W,
                        const float* __restrict__ part, float invcnt,
                        const float* __restrict__ gamma, const float* __restrict__ beta,
                        float* __restrict__ Wf, float* __restrict__ rvB) {
    __shared__ float st[12];
    int c = threadIdx.x;
    if (c < 12) {
        float a = 0.f;
        for (int b = 0; b < B0; ++b) a += part[b * 12 + c];
        st[c] = a;
    }
    __syncthreads();
    float acc = 0.f;
    for (int k = 0; k < 6; ++k) {
        float m = st[k] * invcnt;
        float var = st[6 + k] * invcnt - m * m;
        float A = gamma[k] * rsqrtf(var + BN_EPS);
        float B = beta[k] - m * A;
        float w = W[k * HID + c];
        Wf[k * HID + c] = A * w;
        acc = fmaf(B, w, acc);
    }
    rvB[c] = acc;
}

// -------- fold for K=256: FB blocks; block b transforms k-slice, block 0 does rv --
__global__ void k_fold256(const float* __restrict__ W,
                          const float* __restrict__ partL /* SLABS*512 */, float invcnt,
                          const float* __restrict__ gamma, const float* __restrict__ beta,
                          u16* __restrict__ WhiT, u16* __restrict__ WloT,
                          float* __restrict__ rv) {
    __shared__ float ss[HID], sq[HID];
    int c = threadIdx.x;
    {
        float a = 0.f, b = 0.f;
#pragma unroll 4
        for (int bb = 0; bb < SLABS; ++bb) {
            a += partL[bb * 512 + c];
            b += partL[bb * 512 + HID + c];
        }
        ss[c] = a; sq[c] = b;
    }
    __syncthreads();
    const int k0 = blockIdx.x * (HID / FB);
#pragma unroll
    for (int kk = 0; kk < HID / FB; ++kk) {
        int k = k0 + kk;
        float m = ss[k] * invcnt;
        float var = sq[k] * invcnt - m * m;
        float A = gamma[k] * rsqrtf(var + BN_EPS);
        float w = W[k * HID + c];
        float wf = A * w;
        u16 hi = f2bf(wf);
        WhiT[c * HID + k] = hi;
        WloT[c * HID + k] = f2bf(wf - bf2f(hi));
    }
    if (blockIdx.x == 0) {
        float acc = 0.f;
        for (int k = 0; k < HID; ++k) {
            float m = ss[k] * invcnt;
            float var = sq[k] * invcnt - m * m;
            float A = gamma[k] * rsqrtf(var + BN_EPS);
            float B = beta[k] - m * A;
            acc = fmaf(B, W[k * HID + c], acc);
        }
        rv[c] = acc;
    }
}

// ------- layer 1 FUSED: aggregation + tiny GEMM + relu + stats; grid-stride ------
__global__ __launch_bounds__(256) void k_l1fused(
    const float* __restrict__ pos, const float* __restrict__ nrm,
    const int* __restrict__ ptr, const int* __restrict__ esrc,
    const float* __restrict__ dinv, const float* __restrict__ Wf,
    const float* __restrict__ rvB, const float* __restrict__ b1,
    u16* __restrict__ out, float* __restrict__ partL) {
    const int wv = threadIdx.x >> 6;
    const int ln = threadIdx.x & 63;
    float w[6][4], rv4[4], bb4[4];
#pragma unroll
    for (int k = 0; k < 6; ++k) {
        float4 t = *reinterpret_cast<const float4*>(&Wf[k * HID + ln * 4]);
        w[k][0] = t.x; w[k][1] = t.y; w[k][2] = t.z; w[k][3] = t.w;
    }
    {
        float4 t = *reinterpret_cast<const float4*>(&rvB[ln * 4]);
        rv4[0] = t.x; rv4[1] = t.y; rv4[2] = t.z; rv4[3] = t.w;
        float4 u = *reinterpret_cast<const float4*>(&b1[ln * 4]);
        bb4[0] = u.x; bb4[1] = u.y; bb4[2] = u.z; bb4[3] = u.w;
    }
    float ssr[4] = {0, 0, 0, 0}, qqr[4] = {0, 0, 0, 0};
    for (int n = blockIdx.x * 4 + wv; n < N_NODES; n += AGB * 4) {
        const float dn = dinv[n];
        float z0 = 0, z1 = 0, z2 = 0, z3 = 0, z4 = 0, z5 = 0, t = 0;
        const int s_ = ptr[n], e_ = ptr[n + 1];
        for (int e = s_ + ln; e < e_; e += 64) {
            int src = esrc[e];
            float we = dn * dinv[src];
            z0 = fmaf(we, pos[src * 3 + 0], z0);
            z1 = fmaf(we, pos[src * 3 + 1], z1);
            z2 = fmaf(we, pos[src * 3 + 2], z2);
            z3 = fmaf(we, nrm[src * 3 + 0], z3);
            z4 = fmaf(we, nrm[src * 3 + 1], z4);
            z5 = fmaf(we, nrm[src * 3 + 2], z5);
            t += we;
        }
        if (ln == 0) {
            float sl = dn * dn;
            z0 = fmaf(sl, pos[n * 3 + 0], z0);
            z1 = fmaf(sl, pos[n * 3 + 1], z1);
            z2 = fmaf(sl, pos[n * 3 + 2], z2);
            z3 = fmaf(sl, nrm[n * 3 + 0], z3);
            z4 = fmaf(sl, nrm[n * 3 + 1], z4);
            z5 = fmaf(sl, nrm[n * 3 + 2], z5);
            t += sl;
        }
#pragma unroll
        for (int o = 1; o < 64; o <<= 1) {
            z0 += __shfl_xor(z0, o); z1 += __shfl_xor(z1, o); z2 += __shfl_xor(z2, o);
            z3 += __shfl_xor(z3, o); z4 += __shfl_xor(z4, o); z5 += __shfl_xor(z5, o);
            t  += __shfl_xor(t, o);
        }
        ushort4 o4;
#pragma unroll
        for (int j = 0; j < 4; ++j) {
            float oj = fmaf(t, rv4[j], bb4[j]);
            oj = fmaf(z0, w[0][j], oj); oj = fmaf(z1, w[1][j], oj); oj = fmaf(z2, w[2][j], oj);
            oj = fmaf(z3, w[3][j], oj); oj = fmaf(z4, w[4][j], oj); oj = fmaf(z5, w[5][j], oj);
            oj = fmaxf(oj, 0.f);
            ssr[j] += oj; qqr[j] = fmaf(oj, oj, qqr[j]);
            ((u16*)&o4)[j] = f2bf(oj);
        }
        *reinterpret_cast<ushort4*>(&out[(size_t)n * HID + ln * 4]) = o4;
    }
    __shared__ float sh[4 * 512];
    float* shw = &sh[wv * 512];
#pragma unroll
    for (int j = 0; j < 4; ++j) { shw[ln * 4 + j] = ssr[j]; shw[256 + ln * 4 + j] = qqr[j]; }
    __syncthreads();
    const int t = threadIdx.x;
    float S = sh[t] + sh[512 + t] + sh[1024 + t] + sh[1536 + t];
    float Q = sh[256 + t] + sh[768 + t] + sh[1280 + t] + sh[1792 + t];
    float* slab = &partL[(size_t)(blockIdx.x & (SLABS - 1)) * 512];
    atomicAdd(&slab[t], S);
    atomicAdd(&slab[256 + t], Q);
}

// ------ MFMA GEMM, LDS-staged A tile (padded rows, 2-way-free bank spread) ------
__global__ __launch_bounds__(256) void k_gemm_lds(
    const u16* __restrict__ X, const u16* __restrict__ WhiT,
    const u16* __restrict__ WloT, const float* __restrict__ rv,
    u16* __restrict__ out) {
    __shared__ u16 As[64 * LDSROW];
    const int tid = threadIdx.x;
    const int wv = tid >> 6;
    const int ln = tid & 63;
    const int row0 = blockIdx.x * 64;
    const int lr = ln & 15;
    const int lk = (ln >> 4) * 8;
    const int wcol0 = wv * 64;

#pragma unroll
    for (int i = 0; i < 8; ++i) {
        int chunk = i * 256 + tid;
        int r = chunk >> 5;
        int kc = chunk & 31;
        bf16x8 v = *reinterpret_cast<const bf16x8*>(&X[(size_t)(row0 + r) * HID + kc * 8]);
        *reinterpret_cast<bf16x8*>(&As[r * LDSROW + kc * 8]) = v;
    }
    __syncthreads();

    f32x4 acc[4][4] = {};
    for (int kk = 0; kk < HID; kk += 32) {
        bf16x8 a[4], bh[4], bl[4];
#pragma unroll
        for (int i = 0; i < 4; ++i)
            a[i] = *reinterpret_cast<const bf16x8*>(&As[(i * 16 + lr) * LDSROW + kk + lk]);
#pragma unroll
        for (int c = 0; c < 4; ++c) {
            int col = wcol0 + c * 16 + lr;
            bh[c] = *reinterpret_cast<const bf16x8*>(&WhiT[(size_t)col * HID + kk + lk]);
            bl[c] = *reinterpret_cast<const bf16x8*>(&WloT[(size_t)col * HID + kk + lk]);
        }
#pragma unroll
        for (int i = 0; i < 4; ++i)
#pragma unroll
            for (int c = 0; c < 4; ++c) {
                acc[i][c] = __builtin_amdgcn_mfma_f32_16x16x32_bf16(a[i], bh[c], acc[i][c], 0, 0, 0);
                acc[i][c] = __builtin_amdgcn_mfma_f32_16x16x32_bf16(a[i], bl[c], acc[i][c], 0, 0, 0);
            }
    }
    const int crow = (ln >> 4) * 4;
#pragma unroll
    for (int c = 0; c < 4; ++c) {
        int col = wcol0 + c * 16 + lr;
        float rvc = rv[col];
#pragma unroll
        for (int i = 0; i < 4; ++i) {
#pragma unroll
            for (int rg = 0; rg < 4; ++rg) {
                int r = row0 + i * 16 + crow + rg;
                out[(size_t)r * HID + col] = f2bf(acc[i][c][rg] + rvc);
            }
        }
    }
}

// ---- gather body shared by k_agg / k_aggpool: returns relu(S.xw + bias) ----
__device__ __forceinline__ void agg_node(const u16* __restrict__ xw,
                                         const int* __restrict__ ptr,
                                         const int* __restrict__ esrc,
                                         const float* __restrict__ dinv,
                                         int n, int ln, const float4& b,
                                         float& a0, float& a1, float& a2, float& a3) {
    const float dn = dinv[n];
    float4 v = ld_bf16x4(&xw[(size_t)n * HID + ln * 4]);
    const float sl = dn * dn;
    a0 = v.x * sl; a1 = v.y * sl; a2 = v.z * sl; a3 = v.w * sl;
    const int s = ptr[n], e = ptr[n + 1];
    for (int bs = s; bs < e; bs += 64) {
        const int cnt = (e - bs < 64) ? e - bs : 64;
        int myidx = 0;
        float myw = 0.f;
        if (ln < cnt) {
            myidx = esrc[bs + ln];
            myw = dinv[myidx] * dn;
        }
        int j = 0;
        for (; j + 7 < cnt; j += 8) {
            int   s0 = __shfl(myidx, j),     s1 = __shfl(myidx, j + 1);
            int   s2 = __shfl(myidx, j + 2), s3 = __shfl(myidx, j + 3);
            int   s4 = __shfl(myidx, j + 4), s5 = __shfl(myidx, j + 5);
            int   s6 = __shfl(myidx, j + 6), s7 = __shfl(myidx, j + 7);
            float w0 = __shfl(myw, j),       w1 = __shfl(myw, j + 1);
            float w2 = __shfl(myw, j + 2),   w3 = __shfl(myw, j + 3);
            float w4 = __shfl(myw, j + 4),   w5 = __shfl(myw, j + 5);
            float w6 = __shfl(myw, j + 6),   w7 = __shfl(myw, j + 7);
            float4 u0 = ld_bf16x4(&xw[(size_t)s0 * HID + ln * 4]);
            float4 u1 = ld_bf16x4(&xw[(size_t)s1 * HID + ln * 4]);
            float4 u2 = ld_bf16x4(&xw[(size_t)s2 * HID + ln * 4]);
            float4 u3 = ld_bf16x4(&xw[(size_t)s3 * HID + ln * 4]);
            float4 u4 = ld_bf16x4(&xw[(size_t)s4 * HID + ln * 4]);
            float4 u5 = ld_bf16x4(&xw[(size_t)s5 * HID + ln * 4]);
            float4 u6 = ld_bf16x4(&xw[(size_t)s6 * HID + ln * 4]);
            float4 u7 = ld_bf16x4(&xw[(size_t)s7 * HID + ln * 4]);
            a0 = fmaf(w0, u0.x, a0); a1 = fmaf(w0, u0.y, a1);
            a2 = fmaf(w0, u0.z, a2); a3 = fmaf(w0, u0.w, a3);
            a0 = fmaf(w1, u1.x, a0); a1 = fmaf(w1, u1.y, a1);
            a2 = fmaf(w1, u1.z, a2); a3 = fmaf(w1, u1.w, a3);
            a0 = fmaf(w2, u2.x, a0); a1 = fmaf(w2, u2.y, a1);
            a2 = fmaf(w2, u2.z, a2); a3 = fmaf(w2, u2.w, a3);
            a0 = fmaf(w3, u3.x, a0); a1 = fmaf(w3, u3.y, a1);
            a2 = fmaf(w3, u3.z, a2); a3 = fmaf(w3, u3.w, a3);
            a0 = fmaf(w4, u4.x, a0); a1 = fmaf(w4, u4.y, a1);
            a2 = fmaf(w4, u4.z, a2); a3 = fmaf(w4, u4.w, a3);
            a0 = fmaf(w5, u5.x, a0); a1 = fmaf(w5, u5.y, a1);
            a2 = fmaf(w5, u5.z, a2); a3 = fmaf(w5, u5.w, a3);
            a0 = fmaf(w6, u6.x, a0); a1 = fmaf(w6, u6.y, a1);
            a2 = fmaf(w6, u6.z, a2); a3 = fmaf(w6, u6.w, a3);
            a0 = fmaf(w7, u7.x, a0); a1 = fmaf(w7, u7.y, a1);
            a2 = fmaf(w7, u7.z, a2); a3 = fmaf(w7, u7.w, a3);
        }
        for (; j < cnt; ++j) {
            int   s0 = __shfl(myidx, j);
            float w0 = __shfl(myw, j);
            float4 u0 = ld_bf16x4(&xw[(size_t)s0 * HID + ln * 4]);
            a0 = fmaf(w0, u0.x, a0); a1 = fmaf(w0, u0.y, a1);
            a2 = fmaf(w0, u0.z, a2); a3 = fmaf(w0, u0.w, a3);
        }
    }
    a0 = fmaxf(a0 + b.x, 0.f);
    a1 = fmaxf(a1 + b.y, 0.f);
    a2 = fmaxf(a2 + b.z, 0.f);
    a3 = fmaxf(a3 + b.w, 0.f);
}

// ---- aggregation + stats; grid-stride (AGB blocks, 2 HW scheduling waves) ----
__global__ __launch_bounds__(256) void k_agg(
    const u16* __restrict__ xw, const int* __restrict__ ptr,
    const int* __restrict__ esrc, const float* __restrict__ dinv,
    const float* __restrict__ bias, u16* __restrict__ y,
    float* __restrict__ partL) {
    const int wv = threadIdx.x >> 6;
    const int ln = threadIdx.x & 63;
    float4 b = *reinterpret_cast<const float4*>(&bias[ln * 4]);
    float ssr[4] = {0, 0, 0, 0}, qqr[4] = {0, 0, 0, 0};
    for (int g = blockIdx.x; g < NGRP; g += AGB) {
        const int n = g * 4 + wv;
        float a0, a1, a2, a3;
        agg_node(xw, ptr, esrc, dinv, n, ln, b, a0, a1, a2, a3);
        ssr[0] += a0; qqr[0] = fmaf(a0, a0, qqr[0]);
        ssr[1] += a1; qqr[1] = fmaf(a1, a1, qqr[1]);
        ssr[2] += a2; qqr[2] = fmaf(a2, a2, qqr[2]);
        ssr[3] += a3; qqr[3] = fmaf(a3, a3, qqr[3]);
        ushort4 o;
        o.x = f2bf(a0); o.y = f2bf(a1); o.z = f2bf(a2); o.w = f2bf(a3);
        *reinterpret_cast<ushort4*>(&y[(size_t)n * HID + ln * 4]) = o;
    }
    __shared__ float sh[4 * 512];
    float* shw = &sh[wv * 512];
#pragma unroll
    for (int j = 0; j < 4; ++j) { shw[ln * 4 + j] = ssr[j]; shw[256 + ln * 4 + j] = qqr[j]; }
    __syncthreads();
    const int t = threadIdx.x;
    float S = sh[t] + sh[512 + t] + sh[1024 + t] + sh[1536 + t];
    float Q = sh[256 + t] + sh[768 + t] + sh[1280 + t] + sh[1792 + t];
    float* slab = &partL[(size_t)(blockIdx.x & (SLABS - 1)) * 512];
    atomicAdd(&slab[t], S);
    atomicAdd(&slab[256 + t], Q);
}

// ---- LAST layer: aggregation + stats + fused pool (contiguous chunks, no y) ----
__global__ __launch_bounds__(256) void k_aggpool(
    const u16* __restrict__ xw, const int* __restrict__ ptr,
    const int* __restrict__ esrc, const float* __restrict__ dinv,
    const float* __restrict__ bias, const int* __restrict__ batch,
    float* __restrict__ partL, float* __restrict__ ps) {
    const int wv = threadIdx.x >> 6;
    const int ln = threadIdx.x & 63;
    float4 b = *reinterpret_cast<const float4*>(&bias[ln * 4]);
    float ssr[4] = {0, 0, 0, 0}, qqr[4] = {0, 0, 0, 0};
    const int n0 = blockIdx.x * PCH;
    const int n1 = (n0 + PCH < N_NODES) ? n0 + PCH : N_NODES;
    int curg = -1;
    float p0 = 0, p1 = 0, p2 = 0, p3 = 0;
    for (int n = n0 + wv; n < n1; n += 4) {
        float a0, a1, a2, a3;
        agg_node(xw, ptr, esrc, dinv, n, ln, b, a0, a1, a2, a3);
        ssr[0] += a0; qqr[0] = fmaf(a0, a0, qqr[0]);
        ssr[1] += a1; qqr[1] = fmaf(a1, a1, qqr[1]);
        ssr[2] += a2; qqr[2] = fmaf(a2, a2, qqr[2]);
        ssr[3] += a3; qqr[3] = fmaf(a3, a3, qqr[3]);
        int g = batch[n];   // wave-uniform
        if (g != curg) {
            if (curg >= 0) {
                atomicAdd(&ps[curg * HID + ln * 4 + 0], p0);
                atomicAdd(&ps[curg * HID + ln * 4 + 1], p1);
                atomicAdd(&ps[curg * HID + ln * 4 + 2], p2);
                atomicAdd(&ps[curg * HID + ln * 4 + 3], p3);
            }
            curg = g;
            p0 = p1 = p2 = p3 = 0.f;
        }
        p0 += a0; p1 += a1; p2 += a2; p3 += a3;
    }
    if (curg >= 0) {
        atomicAdd(&ps[curg * HID + ln * 4 + 0], p0);
        atomicAdd(&ps[curg * HID + ln * 4 + 1], p1);
        atomicAdd(&ps[curg * HID + ln * 4 + 2], p2);
        atomicAdd(&ps[curg * HID + ln * 4 + 3], p3);
    }
    __shared__ float sh[4 * 512];
    float* shw = &sh[wv * 512];
#pragma unroll
    for (int j = 0; j < 4; ++j) { shw[ln * 4 + j] = ssr[j]; shw[256 + ln * 4 + j] = qqr[j]; }
    __syncthreads();
    const int t = threadIdx.x;
    float S = sh[t] + sh[512 + t] + sh[1024 + t] + sh[1536 + t];
    float Q = sh[256 + t] + sh[768 + t] + sh[1280 + t] + sh[1792 + t];
    float* slab = &partL[(size_t)(blockIdx.x & (SLABS - 1)) * 512];
    atomicAdd(&slab[t], S);
    atomicAdd(&slab[256 + t], Q);
}

// ---------------- finalize: BN4 affine on pooled sums (reads slabs) ----------------
__global__ void k_final(const float* __restrict__ ps, const int* __restrict__ cg,
                        const float* __restrict__ partL, const float* __restrict__ gamma,
                        const float* __restrict__ beta, float* __restrict__ out) {
    __shared__ float ss[HID], sq[HID];
    const int c = threadIdx.x;
    {
        float a = 0.f, b = 0.f;
#pragma unroll 4
        for (int bb = 0; bb < SLABS; ++bb) {
            a += partL[bb * 512 + c];
            b += partL[bb * 512 + HID + c];
        }
        ss[c] = a; sq[c] = b;
    }
    __syncthreads();
    const float invn = 1.0f / (float)N_NODES;
    float m = ss[c] * invn;
    float var = sq[c] * invn - m * m;
    float A = gamma[c] * rsqrtf(var + BN_EPS);
    float B = beta[c] - m * A;
    for (int g = 0; g < NG; ++g) {
        float cn = (float)cg[g];
        float val = (A * ps[g * HID + c] + cn * B) / fmaxf(cn, 1.0f);
        out[g * HID + c] = val;
    }
}

extern "C" void kernel_launch(void* const* d_in, const int* in_sizes, int n_in,
                              void* d_out, int out_size, void* d_ws, size_t ws_size,
                              hipStream_t stream) {
    const float* pos   = (const float*)d_in[0];
    const float* nrm   = (const float*)d_in[1];
    const int*   ei    = (const int*)d_in[2];
    const int*   batch = (const int*)d_in[3];
    const float* bn0g  = (const float*)d_in[4];
    const float* bn0b  = (const float*)d_in[5];
    const float* W[4]   = {(const float*)d_in[6],  (const float*)d_in[10], (const float*)d_in[14], (const float*)d_in[18]};
    const float* bb[4]  = {(const float*)d_in[7],  (const float*)d_in[11], (const float*)d_in[15], (const float*)d_in[19]};
    const float* bg[4]  = {(const float*)d_in[8],  (const float*)d_in[12], (const float*)d_in[16], (const float*)d_in[20]};
    const float* bbt[4] = {(const float*)d_in[9],  (const float*)d_in[13], (const float*)d_in[17], (const float*)d_in[21]};

    char* wp = (char*)d_ws;
    auto alloc = [&](size_t bytes) {
        char* p = wp;
        wp += (bytes + 255) & ~(size_t)255;
        return p;
    };
    float* dinv  = (float*)alloc((size_t)N_NODES * 4);
    int*   cnt   = (int*)  alloc((size_t)N_NODES * 4);
    int*   ptr   = (int*)  alloc((size_t)(N_NODES + 1) * 4);
    int*   ptr2  = (int*)  alloc((size_t)N_NODES * 4);
    int*   esrc  = (int*)  alloc((size_t)N_EDGES * 4);
    int*   bsum  = (int*)  alloc((size_t)NB * 4);
    int*   boff  = (int*)  alloc((size_t)NB * 4);
    u16*   bufA  = (u16*)  alloc((size_t)NPAD * HID * 2);
    u16*   bufB  = (u16*)  alloc((size_t)NPAD * HID * 2);
    float* part0 = (float*)alloc((size_t)B0 * 12 * 4);
    float* partQ = (float*)alloc((size_t)4 * SLABS * 512 * 4);   // 4 ping-pong stat buffers
    float* Wf1   = (float*)alloc((size_t)6 * HID * 4);
    u16*   WhiT  = (u16*)  alloc((size_t)HID * HID * 2);
    u16*   WloT  = (u16*)  alloc((size_t)HID * HID * 2);
    float* rv    = (float*)alloc(HID * 4);
    float* psz   = (float*)alloc((size_t)(NG * HID + NG) * 4);
    float* ps    = psz;
    int*   cg    = (int*)(psz + NG * HID);
    (void)ws_size; (void)in_sizes; (void)n_in; (void)out_size;

    const int* rowi = ei;
    const int* coli = ei + N_EDGES;

    hipMemsetAsync(cnt, 0, (size_t)N_NODES * 4, stream);
    hipMemsetAsync(psz, 0, (size_t)(NG * HID + NG) * 4, stream);
    hipMemsetAsync(partQ, 0, (size_t)4 * SLABS * 512 * 4, stream);

    // CSR + norms (parallel 3-pass scan)
    k_count<<<2048, 256, 0, stream>>>(coli, cnt);
    k_scanA<<<NB, 256, 0, stream>>>(cnt, bsum);
    k_scanB<<<1, 512, 0, stream>>>(bsum, boff, &ptr[N_NODES]);
    k_scanC<<<NB, 256, 0, stream>>>(cnt, boff, ptr, ptr2, dinv);
    for (int p = 0; p < 4; ++p)
        k_fillp<<<1024, 256, 0, stream>>>(rowi, coli, ptr2, esrc, p * FPART);

    // layer 1: fused raw-space aggregation + BN0-folded tiny GEMM + stats
    k_bn0stats<<<B0, 256, 0, stream>>>(pos, nrm, batch, part0, cg);
    k_fold6<<<1, 256, 0, stream>>>(W[0], part0, 1.0f / (float)N_NODES, bn0g, bn0b, Wf1, rv);
    k_l1fused<<<AGB, 256, 0, stream>>>(pos, nrm, ptr, esrc, dinv, Wf1, rv, bb[0], bufA,
                                       &partQ[0]);

    // layers 2..3: fold -> MFMA gemm -> aggregate(+stats), ping-pong stat buffers
    for (int l = 0; l < 2; ++l) {
        k_fold256<<<FB, 256, 0, stream>>>(W[l + 1], &partQ[(size_t)l * SLABS * 512],
                                          1.0f / (float)N_NODES, bg[l], bbt[l],
                                          WhiT, WloT, rv);
        k_gemm_lds<<<NPAD / 64, 256, 0, stream>>>(bufA, WhiT, WloT, rv, bufB);
        k_agg<<<AGB, 256, 0, stream>>>(bufB, ptr, esrc, dinv, bb[l + 1], bufA,
                                       &partQ[(size_t)(l + 1) * SLABS * 512]);
    }

    // layer 4: fold -> gemm -> aggregate + fused pool (no y write)
    k_fold256<<<FB, 256, 0, stream>>>(W[3], &partQ[(size_t)2 * SLABS * 512],
                                      1.0f / (float)N_NODES, bg[2], bbt[2],
                                      WhiT, WloT, rv);
    k_gemm_lds<<<NPAD / 64, 256, 0, stream>>>(bufA, WhiT, WloT, rv, bufB);
    k_aggpool<<<PBLK, 256, 0, stream>>>(bufB, ptr, esrc, dinv, bb[3], batch,
                                        &partQ[(size_t)3 * SLABS * 512], ps);

    // final: BN4 applied analytically on pooled sums
    k_final<<<1, 256, 0, stream>>>(ps, cg, &partQ[(size_t)3 * SLABS * 512],
                                   bg[3], bbt[3], (float*)d_out);
}